// Round 2
// baseline (2182.422 us; speedup 1.0000x reference)
//
#include <hip/hip_runtime.h>
#include <hip/hip_bf16.h>

#define VOCAB  400000
#define EMB    300
#define HIDDEN 128
#define OUT    3
#define SEQ    4096
#define SPB    8   // sequences per block in the xproj kernel

// ---------------------------------------------------------------------------
// Kernel A: xproj[s][i] = b_ih[i] + dot(weights[X[s]], W_ih[i])
// grid = SEQ/SPB blocks x 128 threads. Each block stages SPB embedding rows
// in LDS (float4), each thread owns one output row i and SPB accumulators so
// each W_ih element is read once per SPB outputs.
// ---------------------------------------------------------------------------
__global__ __launch_bounds__(128) void xproj_kernel(
    const int* __restrict__ X, const float* __restrict__ weights,
    const float* __restrict__ W_ih, const float* __restrict__ b_ih,
    float* __restrict__ xproj)
{
    __shared__ float emb[SPB][EMB];
    __shared__ int xs[SPB];
    const int tid = threadIdx.x;
    const int s0 = blockIdx.x * SPB;

    if (tid < SPB) xs[tid] = X[s0 + tid];
    __syncthreads();

    // stage embeddings as float4 (EMB=300 divisible by 4; rows 1200B -> 16B aligned)
    {
        const float4* w4 = (const float4*)weights;
        float4* e4 = (float4*)&emb[0][0];
        for (int i = tid; i < SPB * (EMB / 4); i += 128) {
            int s = i / (EMB / 4);
            int r = i - s * (EMB / 4);
            e4[i] = w4[(size_t)xs[s] * (EMB / 4) + r];
        }
    }
    __syncthreads();

    const float4* wrow = (const float4*)(W_ih + tid * EMB);
    float acc[SPB];
    #pragma unroll
    for (int s = 0; s < SPB; ++s) acc[s] = 0.f;

    #pragma unroll 5
    for (int r = 0; r < EMB / 4; ++r) {
        float4 w = wrow[r];
        #pragma unroll
        for (int s = 0; s < SPB; ++s) {
            float4 e = *(const float4*)&emb[s][4 * r];   // broadcast read
            acc[s] += w.x * e.x;
            acc[s] += w.y * e.y;
            acc[s] += w.z * e.z;
            acc[s] += w.w * e.w;
        }
    }

    const float b = b_ih[tid];
    #pragma unroll
    for (int s = 0; s < SPB; ++s)
        xproj[(size_t)(s0 + s) * HIDDEN + tid] = acc[s] + b;
}

// ---------------------------------------------------------------------------
// Kernel B: the sequential Elman scan + fc + log_softmax.
// 1 block x 512 threads (8 waves, 2 per SIMD — TLP hides LDS latency while
// per-SIMD FMA issue stays at the 128 cy/step fp32 floor).
// Thread group (4o..4o+3): each quarter computes 32 MACs of output o's dot
// product (W_hh quarter-row in 8 float4 regs), combined via __shfl_xor(1),
// __shfl_xor(2) — in-wave, no extra barrier.
// h double-buffered in LDS -> exactly one __syncthreads() per step.
// xp software-prefetched one step ahead (index clamped: no OOB read).
// ---------------------------------------------------------------------------
__global__ __launch_bounds__(512) void rnn_scan_kernel(
    const float* __restrict__ xproj, const float* __restrict__ W_hh,
    const float* __restrict__ b_hh, const float* __restrict__ W_fc,
    const float* __restrict__ b_fc, float* __restrict__ out)
{
    __shared__ float h_lds[2][HIDDEN];
    __shared__ float lg[OUT];

    const int tid = threadIdx.x;
    const int o   = tid >> 2;      // output element 0..127
    const int q   = tid & 3;       // which 32-wide quarter of the dot product

    // W_hh[o][q*32 .. q*32+31] -> 8 float4 in registers (one-time load)
    float4 w[8];
    {
        const float4* wr = (const float4*)(W_hh + o * HIDDEN + q * 32);
        #pragma unroll
        for (int r = 0; r < 8; ++r) w[r] = wr[r];
    }
    const float bh = b_hh[o];

    if (tid < HIDDEN) h_lds[0][tid] = 0.f;   // h0 = 0
    float xp_cur = xproj[o];                  // xp for t=0
    __syncthreads();

    int cur = 0;
    for (int t = 0; t < SEQ; ++t) {
        // prefetch next step's xp (clamped; last-iter value is never used)
        const int tn = (t < SEQ - 1) ? t + 1 : t;
        float xp_nxt = xproj[(size_t)tn * HIDDEN + o];

        const float4* hb = (const float4*)&h_lds[cur][q * 32];
        float a0 = 0.f, a1 = 0.f, a2 = 0.f, a3 = 0.f;
        #pragma unroll
        for (int r = 0; r < 8; ++r) {
            float4 hv = hb[r];               // 16-lane broadcast read
            a0 += hv.x * w[r].x;
            a1 += hv.y * w[r].y;
            a2 += hv.z * w[r].z;
            a3 += hv.w * w[r].w;
        }
        float acc = (a0 + a1) + (a2 + a3);
        acc += __shfl_xor(acc, 1);           // combine quarters (in-wave)
        acc += __shfl_xor(acc, 2);

        if (q == 0) {
            float z = acc + xp_cur + bh;
            z = fminf(fmaxf(z, -15.f), 15.f);
            // tanh(z) = (e^{2z}-1)/(e^{2z}+1)
            float e = __expf(2.f * z);
            h_lds[cur ^ 1][o] = (e - 1.f) * __builtin_amdgcn_rcpf(e + 1.f);
        }
        __syncthreads();                     // single barrier per step
        cur ^= 1;
        xp_cur = xp_nxt;
    }

    // logits + log_softmax (tail, negligible)
    if (tid < OUT) {
        float a = b_fc[tid];
        const float* wf = W_fc + tid * HIDDEN;
        #pragma unroll 4
        for (int j = 0; j < HIDDEN; ++j) a += h_lds[cur][j] * wf[j];
        lg[tid] = a;
    }
    __syncthreads();
    if (tid == 0) {
        float m = fmaxf(lg[0], fmaxf(lg[1], lg[2]));
        float s = expf(lg[0] - m) + expf(lg[1] - m) + expf(lg[2] - m);
        float lse = m + logf(s);
        out[0] = lg[0] - lse;
        out[1] = lg[1] - lse;
        out[2] = lg[2] - lse;
    }
}

// ---------------------------------------------------------------------------
extern "C" void kernel_launch(void* const* d_in, const int* in_sizes, int n_in,
                              void* d_out, int out_size, void* d_ws, size_t ws_size,
                              hipStream_t stream) {
    const int*   X       = (const int*)d_in[0];
    const float* weights = (const float*)d_in[1];
    const float* W_ih    = (const float*)d_in[2];
    const float* b_ih    = (const float*)d_in[3];
    const float* W_hh    = (const float*)d_in[4];
    const float* b_hh    = (const float*)d_in[5];
    const float* W_fc    = (const float*)d_in[6];
    const float* b_fc    = (const float*)d_in[7];
    float* out   = (float*)d_out;
    float* xproj = (float*)d_ws;   // needs SEQ*HIDDEN*4 = 2 MB of scratch

    xproj_kernel<<<SEQ / SPB, 128, 0, stream>>>(X, weights, W_ih, b_ih, xproj);
    rnn_scan_kernel<<<1, 512, 0, stream>>>(xproj, W_hh, b_hh, W_fc, b_fc, out);
}

// Round 4
// 1832.520 us; speedup vs baseline: 1.1909x; 1.1909x over previous
//
#include <hip/hip_runtime.h>
#include <hip/hip_bf16.h>

#define VOCAB  400000
#define EMB    300
#define HIDDEN 128
#define OUT    3
#define SEQ    4096
#define SPB    8   // sequences per block in the xproj kernel

// ---------------------------------------------------------------------------
// Kernel A: xproj[s][i] = b_ih[i] + dot(weights[X[s]], W_ih[i])
// grid = SEQ/SPB blocks x 128 threads. Each block stages SPB embedding rows
// in LDS (float4), each thread owns one output row i and SPB accumulators.
// All emb reads are wave-uniform broadcasts (conflict-free).
// ---------------------------------------------------------------------------
__global__ __launch_bounds__(128) void xproj_kernel(
    const int* __restrict__ X, const float* __restrict__ weights,
    const float* __restrict__ W_ih, const float* __restrict__ b_ih,
    float* __restrict__ xproj)
{
    __shared__ float emb[SPB][EMB];
    __shared__ int xs[SPB];
    const int tid = threadIdx.x;
    const int s0 = blockIdx.x * SPB;

    if (tid < SPB) xs[tid] = X[s0 + tid];
    __syncthreads();

    {
        const float4* w4 = (const float4*)weights;
        float4* e4 = (float4*)&emb[0][0];
        for (int i = tid; i < SPB * (EMB / 4); i += 128) {
            int s = i / (EMB / 4);
            int r = i - s * (EMB / 4);
            e4[i] = w4[(size_t)xs[s] * (EMB / 4) + r];
        }
    }
    __syncthreads();

    const float4* wrow = (const float4*)(W_ih + tid * EMB);
    float acc[SPB];
    #pragma unroll
    for (int s = 0; s < SPB; ++s) acc[s] = 0.f;

    #pragma unroll 5
    for (int r = 0; r < EMB / 4; ++r) {
        float4 w = wrow[r];
        #pragma unroll
        for (int s = 0; s < SPB; ++s) {
            float4 e = *(const float4*)&emb[s][4 * r];   // uniform broadcast
            acc[s] += w.x * e.x;
            acc[s] += w.y * e.y;
            acc[s] += w.z * e.z;
            acc[s] += w.w * e.w;
        }
    }

    const float b = b_ih[tid];
    #pragma unroll
    for (int s = 0; s < SPB; ++s)
        xproj[(size_t)(s0 + s) * HIDDEN + tid] = acc[s] + b;
}

// ---------------------------------------------------------------------------
// Quad butterfly sum via DPP quad_perm (full-rate VALU, no LDS round-trip).
// 0xB1 = quad_perm [1,0,3,2] (xor 1); 0x4E = quad_perm [2,3,0,1] (xor 2).
// ---------------------------------------------------------------------------
__device__ __forceinline__ float quad_reduce_add(float x) {
    int t = __builtin_amdgcn_update_dpp(0, __float_as_int(x), 0xB1, 0xF, 0xF, true);
    x += __int_as_float(t);
    t = __builtin_amdgcn_update_dpp(0, __float_as_int(x), 0x4E, 0xF, 0xF, true);
    x += __int_as_float(t);
    return x;
}

// ---------------------------------------------------------------------------
// Kernel B: sequential Elman scan + fc + log_softmax.
// 1 block x 512 threads (8 waves, 2/SIMD). Thread (o=tid>>2, q=tid&3).
// Quarter q owns the INTERLEAVED float4 columns {4*rr+q : rr=0..7} of W_hh
// row o: at read instr rr the 4 q-groups hit dword banks 16rr+{0..15} mod 32
// -> 16 distinct banks, 16-lane same-address broadcast each, ZERO conflicts,
// and the addresses are linear (base + q*16 + rr*64 bytes -> imm offsets).
// Quad partials combined with 2 DPP adds. One __syncthreads() per step.
// xp prefetched 2 steps ahead (xproj may live in remote-XCD L2 / L3).
// ---------------------------------------------------------------------------
__global__ __launch_bounds__(512) void rnn_scan_kernel(
    const float* __restrict__ xproj, const float* __restrict__ W_hh,
    const float* __restrict__ b_hh, const float* __restrict__ W_fc,
    const float* __restrict__ b_fc, float* __restrict__ out)
{
    __shared__ float h_lds[2][HIDDEN];
    __shared__ float lg[OUT];

    const int tid = threadIdx.x;
    const int o   = tid >> 2;      // output element 0..127
    const int q   = tid & 3;       // interleave phase

    // W_hh row o, float4 columns 4*rr+q  (compile-time reg indices; permuted
    // one-time global load so the step loop pairs w[rr] with h float4 4*rr+q)
    float4 w[8];
    {
        const float4* wr = (const float4*)(W_hh + o * HIDDEN);
        #pragma unroll
        for (int rr = 0; rr < 8; ++rr) w[rr] = wr[4 * rr + q];
    }
    const float bh = b_hh[o];

    if (tid < HIDDEN) h_lds[0][tid] = 0.f;   // h0 = 0
    float xp0 = xproj[o];                     // xp for t
    float xp1 = xproj[HIDDEN + o];            // xp for t+1
    __syncthreads();

    int cur = 0;
    for (int t = 0; t < SEQ; ++t) {
        // prefetch xp for t+2 (clamped; tail value never used)
        const int tn = (t + 2 < SEQ) ? t + 2 : SEQ - 1;
        float xp2 = xproj[(size_t)tn * HIDDEN + o];

        const float4* hb = (const float4*)&h_lds[cur][0] + q;
        float a0 = 0.f, a1 = 0.f, a2 = 0.f, a3 = 0.f;
        #pragma unroll
        for (int rr = 0; rr < 8; ++rr) {
            float4 hv = hb[4 * rr];          // ds_read_b128, offset rr*64
            a0 += hv.x * w[rr].x;
            a1 += hv.y * w[rr].y;
            a2 += hv.z * w[rr].z;
            a3 += hv.w * w[rr].w;
        }
        float acc = (a0 + a1) + (a2 + a3);
        acc = quad_reduce_add(acc);          // all 4 quad lanes get the sum

        float z = acc + xp0 + bh;
        z = fminf(fmaxf(z, -15.f), 15.f);
        float e = __expf(2.f * z);           // tanh(z) = (e^2z - 1)/(e^2z + 1)
        float hn = (e - 1.f) * __builtin_amdgcn_rcpf(e + 1.f);
        if (q == 0) h_lds[cur ^ 1][o] = hn;  // exec-masked 4B write, no branch

        __syncthreads();                     // single barrier per step
        cur ^= 1;
        xp0 = xp1;
        xp1 = xp2;
    }

    // logits + log_softmax (tail, negligible)
    if (tid < OUT) {
        float a = b_fc[tid];
        const float* wf = W_fc + tid * HIDDEN;
        #pragma unroll 4
        for (int j = 0; j < HIDDEN; ++j) a += h_lds[cur][j] * wf[j];
        lg[tid] = a;
    }
    __syncthreads();
    if (tid == 0) {
        float m = fmaxf(lg[0], fmaxf(lg[1], lg[2]));
        float s = expf(lg[0] - m) + expf(lg[1] - m) + expf(lg[2] - m);
        float lse = m + logf(s);
        out[0] = lg[0] - lse;
        out[1] = lg[1] - lse;
        out[2] = lg[2] - lse;
    }
}

// ---------------------------------------------------------------------------
extern "C" void kernel_launch(void* const* d_in, const int* in_sizes, int n_in,
                              void* d_out, int out_size, void* d_ws, size_t ws_size,
                              hipStream_t stream) {
    const int*   X       = (const int*)d_in[0];
    const float* weights = (const float*)d_in[1];
    const float* W_ih    = (const float*)d_in[2];
    const float* b_ih    = (const float*)d_in[3];
    const float* W_hh    = (const float*)d_in[4];
    const float* b_hh    = (const float*)d_in[5];
    const float* W_fc    = (const float*)d_in[6];
    const float* b_fc    = (const float*)d_in[7];
    float* out   = (float*)d_out;
    float* xproj = (float*)d_ws;   // SEQ*HIDDEN*4 = 2 MB of scratch

    xproj_kernel<<<SEQ / SPB, 128, 0, stream>>>(X, weights, W_ih, b_ih, xproj);
    rnn_scan_kernel<<<1, 512, 0, stream>>>(xproj, W_hh, b_hh, W_fc, b_fc, out);
}